// Round 1
// baseline (535.534 us; speedup 1.0000x reference)
//
#include <hip/hip_runtime.h>

typedef unsigned short u16;
typedef __bf16 bf16x8 __attribute__((ext_vector_type(8)));
typedef float f32x4 __attribute__((ext_vector_type(4)));

// ---------- helpers ----------

__device__ __forceinline__ u16 f2bf(float f) {
  unsigned u = __float_as_uint(f);
  u += 0x7fffu + ((u >> 16) & 1u);   // RNE
  return (u16)(u >> 16);
}

__device__ __forceinline__ void load_lds16(const void* g, void* l) {
  __builtin_amdgcn_global_load_lds(
      (const __attribute__((address_space(1))) void*)g,
      (__attribute__((address_space(3))) void*)l, 16, 0, 0);
}

// ---------- fp32 -> bf16 conversion ----------

__device__ __forceinline__ void conv_seg(const float* __restrict__ s,
                                         u16* __restrict__ d, int n4,
                                         int g, int stride) {
  const float4* s4 = (const float4*)s;
  ushort4* d4 = (ushort4*)d;
  for (int i = g; i < n4; i += stride) {
    float4 v = s4[i];
    d4[i] = make_ushort4(f2bf(v.x), f2bf(v.y), f2bf(v.z), f2bf(v.w));
  }
}

__global__ __launch_bounds__(256) void convert_all(
    const float* __restrict__ hid, const float* __restrict__ wqa,
    const float* __restrict__ wqb, const float* __restrict__ wkva,
    const float* __restrict__ wkvb,
    u16* __restrict__ hid_b, u16* __restrict__ wqa_b, u16* __restrict__ wqb_b,
    u16* __restrict__ wkva_b, u16* __restrict__ wkvb_b) {
  int g = blockIdx.x * 256 + threadIdx.x;
  int stride = gridDim.x * 256;
  conv_seg(hid,  hid_b,  16777216 / 4, g, stride);
  conv_seg(wqa,  wqa_b,   1572864 / 4, g, stride);
  conv_seg(wqb,  wqb_b,   2359296 / 4, g, stride);
  conv_seg(wkva, wkva_b,  1179648 / 4, g, stride);
  conv_seg(wkvb, wkvb_b,  2097152 / 4, g, stride);
}

// ---------- RoPE table: cos/sin[s][i], s in [0,4096), i in [0,32) ----------

__global__ __launch_bounds__(256) void rope_table(float* __restrict__ cosT,
                                                  float* __restrict__ sinT) {
  int idx = blockIdx.x * 256 + threadIdx.x;   // 131072 total
  int s = idx >> 5, i = idx & 31;
  float inv = powf(10000.f, -(float)i / 32.f);
  float f = (float)s * inv;
  float sv, cv;
  sincosf(f, &sv, &cv);
  cosT[idx] = cv;
  sinT[idx] = sv;
}

// ---------- GEMM C = A (M x K, bf16) @ B^T (N x K, bf16) + bias ----------
// MODE 0: plain fp32 store to Cout[M x N] (N bounds-checked)
// MODE 1: q epilogue -> out, fused RoPE on rope wave-tiles
// MODE 2: kv epilogue -> out (k_nope / v channel remap)

template <int MODE>
__global__ __launch_bounds__(256, 2) void gemm_bt(
    const u16* __restrict__ A, const u16* __restrict__ B,
    const float* __restrict__ bias, float* __restrict__ Cout, int N, int K,
    const float* __restrict__ cosT, const float* __restrict__ sinT) {
  __shared__ __align__(16) u16 sA[128 * 64];
  __shared__ __align__(16) u16 sB[128 * 64];
  const int tid = threadIdx.x;
  const int lane = tid & 63;
  const int wave = tid >> 6;
  const int wm = (wave >> 1) * 64;   // wave row offset in tile
  const int wn = (wave & 1) * 64;    // wave col offset in tile
  const int mTile = blockIdx.x * 128;
  const int nTile = blockIdx.y * 128;
  const int lane15 = lane & 15;
  const int quad = lane >> 4;

  f32x4 acc[4][4] = {};

  const int nStages = K >> 6;   // BK = 64
  for (int ks = 0; ks < nStages; ++ks) {
    const int k0 = ks << 6;
    if (ks) __syncthreads();   // previous compute done before overwrite
    // stage A: 128 rows x 64 k (16 KB). unit = 16B; XOR-8 swizzle on k-units.
#pragma unroll
    for (int i = 0; i < 4; ++i) {
      int nu = i * 256 + tid;
      int r = nu >> 3, up = nu & 7;
      int ul = up ^ (r & 7);
      const u16* g = A + (size_t)(mTile + r) * K + (k0 + ul * 8);
      load_lds16(g, &sA[(i * 256 + (wave << 6)) * 8]);
    }
#pragma unroll
    for (int i = 0; i < 4; ++i) {
      int nu = i * 256 + tid;
      int r = nu >> 3, up = nu & 7;
      int ul = up ^ (r & 7);
      int row = nTile + r;
      if (row >= N) row = N - 1;   // clamp (stores are predicated)
      const u16* g = B + (size_t)row * K + (k0 + ul * 8);
      load_lds16(g, &sB[(i * 256 + (wave << 6)) * 8]);
    }
    __syncthreads();
#pragma unroll
    for (int kk = 0; kk < 2; ++kk) {   // two k=32 steps
      bf16x8 af[4], bfv[4];
#pragma unroll
      for (int mi = 0; mi < 4; ++mi) {
        int r = wm + mi * 16 + lane15;
        int up = (kk * 4 + quad) ^ (r & 7);
        af[mi] = *(const bf16x8*)&sA[(r * 8 + up) * 8];
      }
#pragma unroll
      for (int ni = 0; ni < 4; ++ni) {
        int r = wn + ni * 16 + lane15;
        int up = (kk * 4 + quad) ^ (r & 7);
        bfv[ni] = *(const bf16x8*)&sB[(r * 8 + up) * 8];
      }
#pragma unroll
      for (int mi = 0; mi < 4; ++mi)
#pragma unroll
        for (int ni = 0; ni < 4; ++ni)
          acc[mi][ni] = __builtin_amdgcn_mfma_f32_16x16x32_bf16(
              af[mi], bfv[ni], acc[mi][ni], 0, 0, 0);
    }
  }

  // ---------- epilogue ----------
  float bv[4];
#pragma unroll
  for (int ni = 0; ni < 4; ++ni) {
    int col = nTile + wn + ni * 16 + lane15;
    bv[ni] = (col < N) ? bias[col] : 0.f;
  }

  if (MODE == 0) {
#pragma unroll
    for (int mi = 0; mi < 4; ++mi)
#pragma unroll
      for (int reg = 0; reg < 4; ++reg) {
        int row = mTile + wm + mi * 16 + quad * 4 + reg;
#pragma unroll
        for (int ni = 0; ni < 4; ++ni) {
          int col = nTile + wn + ni * 16 + lane15;
          if (col < N) Cout[(size_t)row * N + col] = acc[mi][ni][reg] + bv[ni];
        }
      }
  } else if (MODE == 1) {
    // q: col = h*192 + j ; j<128 -> q_nope (out ch j), j>=128 -> rope (out ch j)
    const int colW = nTile + wn;          // wave tile is 64-wide, 64-aligned
    const int h = colW / 192;             // uniform across wave tile
    const int jBase = colW % 192;         // 0, 64 (nope) or 128 (rope)
    if (jBase != 128) {
#pragma unroll
      for (int mi = 0; mi < 4; ++mi)
#pragma unroll
        for (int reg = 0; reg < 4; ++reg) {
          int row = mTile + wm + mi * 16 + quad * 4 + reg;
          int bb = row >> 12, ss = row & 4095;
          size_t ob = ((size_t)((bb * 16 + h) * 4096 + ss)) * 512 + jBase;
#pragma unroll
          for (int ni = 0; ni < 4; ++ni)
            Cout[ob + ni * 16 + lane15] = acc[mi][ni][reg] + bv[ni];
        }
    } else {
      // rope: pairs (i, i+32) live in (ni, ni+2) of the same lane
#pragma unroll
      for (int ni = 0; ni < 2; ++ni) {
        int i = ni * 16 + lane15;   // 0..31
#pragma unroll
        for (int mi = 0; mi < 4; ++mi)
#pragma unroll
          for (int reg = 0; reg < 4; ++reg) {
            int row = mTile + wm + mi * 16 + quad * 4 + reg;
            int bb = row >> 12, ss = row & 4095;
            float cv = cosT[ss * 32 + i], sv = sinT[ss * 32 + i];
            float x1 = acc[mi][ni][reg] + bv[ni];
            float x2 = acc[mi][ni + 2][reg] + bv[ni + 2];
            size_t ob = ((size_t)((bb * 16 + h) * 4096 + ss)) * 512 + 128;
            Cout[ob + i] = x1 * cv - x2 * sv;
            Cout[ob + 32 + i] = x2 * cv + x1 * sv;
          }
      }
    }
  } else {
    // kv: col = h*256 + j ; j<128 -> k_nope (ch 192+j), j>=128 -> v (ch 256+j)
    const int colW = nTile + wn;
    const int h = colW >> 8;
    const int jBase = colW & 255;   // 0,64,128,192
    const int chBase = (jBase < 128) ? (192 + jBase) : (256 + jBase);
#pragma unroll
    for (int mi = 0; mi < 4; ++mi)
#pragma unroll
      for (int reg = 0; reg < 4; ++reg) {
        int row = mTile + wm + mi * 16 + quad * 4 + reg;
        int bb = row >> 12, ss = row & 4095;
        size_t ob = ((size_t)((bb * 16 + h) * 4096 + ss)) * 512 + chBase;
#pragma unroll
        for (int ni = 0; ni < 4; ++ni)
          Cout[ob + ni * 16 + lane15] = acc[mi][ni][reg] + bv[ni];
      }
  }
}

// ---------- LayerNorm(q_c), LayerNorm(kv_lr), k_rot broadcast ----------

__device__ __forceinline__ void reduce2(float& s1, float& s2, float* rs,
                                        float* rq) {
#pragma unroll
  for (int off = 32; off > 0; off >>= 1) {
    s1 += __shfl_down(s1, off, 64);
    s2 += __shfl_down(s2, off, 64);
  }
  int lane = threadIdx.x & 63, wave = threadIdx.x >> 6;
  if (lane == 0) { rs[wave] = s1; rq[wave] = s2; }
  __syncthreads();
  s1 = rs[0] + rs[1] + rs[2] + rs[3];
  s2 = rq[0] + rq[1] + rq[2] + rq[3];
  __syncthreads();
}

__global__ __launch_bounds__(256) void ln_rot(
    const float* __restrict__ qc, const float* __restrict__ kvc,
    const float* __restrict__ g_q, const float* __restrict__ b_q,
    const float* __restrict__ g_kv, const float* __restrict__ b_kv,
    u16* __restrict__ q_ln, u16* __restrict__ kv_ln,
    const float* __restrict__ cosT, const float* __restrict__ sinT,
    float* __restrict__ out) {
  __shared__ float rs[4], rq[4];
  __shared__ float rot[64];
  const int t = blockIdx.x;       // token 0..8191
  const int tid = threadIdx.x;
  const int bb = t >> 12, ss = t & 4095;

  // q LayerNorm (768)
  {
    const float* p = qc + (size_t)t * 768;
    float v[3], sum = 0.f, sq = 0.f;
#pragma unroll
    for (int j = 0; j < 3; ++j) {
      v[j] = p[tid + j * 256];
      sum += v[j];
      sq += v[j] * v[j];
    }
    reduce2(sum, sq, rs, rq);
    float mu = sum * (1.f / 768.f);
    float var = sq * (1.f / 768.f) - mu * mu;
    float inv = rsqrtf(var + 1e-5f);
#pragma unroll
    for (int j = 0; j < 3; ++j) {
      int c = tid + j * 256;
      q_ln[(size_t)t * 768 + c] = f2bf((v[j] - mu) * inv * g_q[c] + b_q[c]);
    }
  }
  // kv LayerNorm (512)
  {
    const float* p = kvc + (size_t)t * 576;
    float v[2], sum = 0.f, sq = 0.f;
#pragma unroll
    for (int j = 0; j < 2; ++j) {
      v[j] = p[tid + j * 256];
      sum += v[j];
      sq += v[j] * v[j];
    }
    reduce2(sum, sq, rs, rq);
    float mu = sum * (1.f / 512.f);
    float var = sq * (1.f / 512.f) - mu * mu;
    float inv = rsqrtf(var + 1e-5f);
#pragma unroll
    for (int j = 0; j < 2; ++j) {
      int c = tid + j * 256;
      kv_ln[(size_t)t * 512 + c] = f2bf((v[j] - mu) * inv * g_kv[c] + b_kv[c]);
    }
  }
  // k_rot (64), broadcast to all 16 heads at out channel 320..383
  if (tid < 32) {
    const float* p = kvc + (size_t)t * 576 + 512;
    float k1 = p[tid], k2 = p[tid + 32];
    float cv = cosT[ss * 32 + tid], sv = sinT[ss * 32 + tid];
    rot[tid] = k1 * cv - k2 * sv;
    rot[tid + 32] = k2 * cv + k1 * sv;
  }
  __syncthreads();
  for (int u = tid; u < 1024; u += 256) {
    int h = u >> 6, i2 = u & 63;
    out[((size_t)((bb * 16 + h) * 4096 + ss)) * 512 + 320 + i2] = rot[i2];
  }
}

// ---------- launch ----------

extern "C" void kernel_launch(void* const* d_in, const int* in_sizes, int n_in,
                              void* d_out, int out_size, void* d_ws,
                              size_t ws_size, hipStream_t stream) {
  const float* hidden = (const float*)d_in[0];
  const float* w_qa = (const float*)d_in[1];
  const float* b_qa = (const float*)d_in[2];
  const float* g_qa_ln = (const float*)d_in[3];
  const float* b_qa_ln = (const float*)d_in[4];
  const float* w_qb = (const float*)d_in[5];
  const float* b_qb = (const float*)d_in[6];
  const float* w_kva = (const float*)d_in[7];
  const float* b_kva = (const float*)d_in[8];
  const float* g_kva_ln = (const float*)d_in[9];
  const float* b_kva_ln = (const float*)d_in[10];
  const float* w_kvb = (const float*)d_in[11];
  const float* b_kvb = (const float*)d_in[12];
  float* out = (float*)d_out;

  char* ws = (char*)d_ws;
  u16* hid_bf = (u16*)ws;            ws += (size_t)16777216 * 2;
  u16* wqa_bf = (u16*)ws;            ws += (size_t)1572864 * 2;
  u16* wqb_bf = (u16*)ws;            ws += (size_t)2359296 * 2;
  u16* wkva_bf = (u16*)ws;           ws += (size_t)1179648 * 2;
  u16* wkvb_bf = (u16*)ws;           ws += (size_t)2097152 * 2;
  float* qc = (float*)ws;            ws += (size_t)6291456 * 4;
  float* kvc = (float*)ws;           ws += (size_t)4718592 * 4;
  u16* q_ln = (u16*)ws;              ws += (size_t)6291456 * 2;
  u16* kv_ln = (u16*)ws;             ws += (size_t)4194304 * 2;
  float* cosT = (float*)ws;          ws += (size_t)131072 * 4;
  float* sinT = (float*)ws;          ws += (size_t)131072 * 4;

  convert_all<<<dim3(1024), dim3(256), 0, stream>>>(
      hidden, w_qa, w_qb, w_kva, w_kvb, hid_bf, wqa_bf, wqb_bf, wkva_bf,
      wkvb_bf);
  rope_table<<<dim3(512), dim3(256), 0, stream>>>(cosT, sinT);
  // q_c = hidden @ w_qa^T + b_qa  (8192 x 768, K=2048)
  gemm_bt<0><<<dim3(64, 6), dim3(256), 0, stream>>>(hid_bf, wqa_bf, b_qa, qc,
                                                    768, 2048, cosT, sinT);
  // kv_c = hidden @ w_kva^T + b_kva  (8192 x 576, K=2048)
  gemm_bt<0><<<dim3(64, 5), dim3(256), 0, stream>>>(hid_bf, wkva_bf, b_kva,
                                                    kvc, 576, 2048, cosT, sinT);
  ln_rot<<<dim3(8192), dim3(256), 0, stream>>>(qc, kvc, g_qa_ln, b_qa_ln,
                                               g_kva_ln, b_kva_ln, q_ln, kv_ln,
                                               cosT, sinT, out);
  // q = q_ln @ w_qb^T + b_qb  (8192 x 3072, K=768), fused RoPE
  gemm_bt<1><<<dim3(64, 24), dim3(256), 0, stream>>>(q_ln, wqb_bf, b_qb, out,
                                                     3072, 768, cosT, sinT);
  // kv = kv_ln @ w_kvb^T + b_kvb  (8192 x 4096, K=512)
  gemm_bt<2><<<dim3(64, 32), dim3(256), 0, stream>>>(kv_ln, wkvb_bf, b_kvb, out,
                                                     4096, 512, cosT, sinT);
}

// Round 2
// 473.726 us; speedup vs baseline: 1.1305x; 1.1305x over previous
//
#include <hip/hip_runtime.h>

typedef unsigned short u16;
typedef __bf16 bf16x8 __attribute__((ext_vector_type(8)));
typedef float f32x4 __attribute__((ext_vector_type(4)));

// ---------- helpers ----------

__device__ __forceinline__ u16 f2bf(float f) {
  unsigned u = __float_as_uint(f);
  u += 0x7fffu + ((u >> 16) & 1u);   // RNE
  return (u16)(u >> 16);
}

__device__ __forceinline__ void load_lds16(const void* g, void* l) {
  __builtin_amdgcn_global_load_lds(
      (const __attribute__((address_space(1))) void*)g,
      (__attribute__((address_space(3))) void*)l, 16, 0, 0);
}

__device__ __forceinline__ void conv_seg(const float* __restrict__ s,
                                         u16* __restrict__ d, int n4,
                                         int g, int stride) {
  const float4* s4 = (const float4*)s;
  ushort4* d4 = (ushort4*)d;
  for (int i = g; i < n4; i += stride) {
    float4 v = s4[i];
    d4[i] = make_ushort4(f2bf(v.x), f2bf(v.y), f2bf(v.z), f2bf(v.w));
  }
}

// ---------- prep: fp32->bf16 converts, bias concat, rope table ----------

__global__ __launch_bounds__(256) void prep(
    const float* __restrict__ hid, const float* __restrict__ wqa,
    const float* __restrict__ wkva, const float* __restrict__ wqb,
    const float* __restrict__ wkvb, const float* __restrict__ bqa,
    const float* __restrict__ bkva, u16* __restrict__ hid_b,
    u16* __restrict__ wab_b, u16* __restrict__ wqb_b,
    u16* __restrict__ wkvb_b, float* __restrict__ bias_ab,
    float* __restrict__ cosT, float* __restrict__ sinT) {
  int g = blockIdx.x * 256 + threadIdx.x;
  int stride = gridDim.x * 256;
  conv_seg(hid, hid_b, 4194304, g, stride);
  conv_seg(wqa, wab_b, 393216, g, stride);                 // rows 0..767
  conv_seg(wkva, wab_b + 768 * 2048, 294912, g, stride);   // rows 768..1343
  conv_seg(wqb, wqb_b, 589824, g, stride);
  conv_seg(wkvb, wkvb_b, 524288, g, stride);
  if (g < 1344) bias_ab[g] = (g < 768) ? bqa[g] : bkva[g - 768];
  for (int idx = g; idx < 131072; idx += stride) {
    int s = idx >> 5, i = idx & 31;
    float inv = powf(10000.f, -(float)i / 32.f);
    float f = (float)s * inv;
    float sv, cv;
    sincosf(f, &sv, &cv);
    cosT[idx] = cv;
    sinT[idx] = sv;
  }
}

// ---------- GEMM: C = A(Mx K bf16) @ B^T(N x K bf16) + bias ----------
// WHICH=0: merged q_c|kv_c -> qkvc fp32 (N=1344, stride 1344, K=2048)
// WHICH=1: merged B-gemms -> out; blockIdx.y<24 = Q (K=768, fused RoPE),
//          else KV (K=512)

template <int WHICH>
__global__ __launch_bounds__(256, 2) void gemm_k(
    const u16* __restrict__ A0, const u16* __restrict__ B0,
    const float* __restrict__ bias0, float* __restrict__ C0,
    const u16* __restrict__ qA, const u16* __restrict__ qB,
    const float* __restrict__ qb, const u16* __restrict__ kA,
    const u16* __restrict__ kB, const float* __restrict__ kb,
    float* __restrict__ out, const float* __restrict__ cosT,
    const float* __restrict__ sinT) {
  __shared__ __align__(16) u16 smem[2 * 128 * 64];
  u16* sA = smem;
  u16* sB = smem + 128 * 64;
  const int tid = threadIdx.x;
  const int lane = tid & 63;
  const int wave = tid >> 6;
  const int wm = (wave >> 1) * 64;
  const int wn = (wave & 1) * 64;
  const int lane15 = lane & 15;
  const int quad = lane >> 4;
  const int mTile = blockIdx.x * 128;

  const u16* A;
  const u16* B;
  const float* bias;
  int K, nTile, mode;
  if (WHICH == 0) {
    A = A0; B = B0; bias = bias0; K = 2048; nTile = blockIdx.y * 128; mode = 0;
  } else if (blockIdx.y < 24) {
    A = qA; B = qB; bias = qb; K = 768; nTile = blockIdx.y * 128; mode = 1;
  } else {
    A = kA; B = kB; bias = kb; K = 512; nTile = (blockIdx.y - 24) * 128;
    mode = 2;
  }

  f32x4 acc[4][4] = {};

  const int nStages = K >> 6;
  for (int ks = 0; ks < nStages; ++ks) {
    const int k0 = ks << 6;
    if (ks) __syncthreads();
#pragma unroll
    for (int i = 0; i < 4; ++i) {
      int nu = i * 256 + tid;
      int rr = nu >> 3, u = nu & 7;
      int ul = u ^ (rr & 7);
      load_lds16(A + (size_t)(mTile + rr) * K + (k0 + ul * 8),
                 &sA[(i * 256 + (wave << 6)) * 8]);
    }
#pragma unroll
    for (int i = 0; i < 4; ++i) {
      int nu = i * 256 + tid;
      int rr = nu >> 3, u = nu & 7;
      int ul = u ^ (rr & 7);
      int brow = nTile + rr;
      if (WHICH == 0 && brow >= 1344) brow = 1343;
      load_lds16(B + (size_t)brow * K + (k0 + ul * 8),
                 &sB[(i * 256 + (wave << 6)) * 8]);
    }
    __syncthreads();
#pragma unroll
    for (int kk = 0; kk < 2; ++kk) {
      bf16x8 af[4], bfv[4];
#pragma unroll
      for (int mi = 0; mi < 4; ++mi) {
        int r = wm + mi * 16 + lane15;
        int u = (kk * 4 + quad) ^ (r & 7);
        af[mi] = *(const bf16x8*)&sA[(r * 8 + u) * 8];
      }
#pragma unroll
      for (int ni = 0; ni < 4; ++ni) {
        int r = wn + ni * 16 + lane15;
        int u = (kk * 4 + quad) ^ (r & 7);
        bfv[ni] = *(const bf16x8*)&sB[(r * 8 + u) * 8];
      }
#pragma unroll
      for (int mi = 0; mi < 4; ++mi)
#pragma unroll
        for (int ni = 0; ni < 4; ++ni)
          acc[mi][ni] = __builtin_amdgcn_mfma_f32_16x16x32_bf16(
              af[mi], bfv[ni], acc[mi][ni], 0, 0, 0);
    }
  }

  // ---------- epilogue: bias (+rope), LDS transpose, float4 stores ----------
  const int colW = nTile + wn;
  float bv[4];
#pragma unroll
  for (int ni = 0; ni < 4; ++ni) {
    int col = colW + ni * 16 + lane15;
    if (WHICH == 0)
      bv[ni] = (col < 1344) ? bias[col] : 0.f;
    else
      bv[ni] = bias[col];
  }

  int h = 0, ch0 = 0;
  if (mode == 1) {
    h = colW / 192;
    ch0 = colW % 192;
  } else if (mode == 2) {
    int jb = colW & 255;
    h = colW >> 8;
    ch0 = (jb < 128) ? (192 + jb) : (256 + jb);
  }
  const bool ropeTile = (mode == 1) && (ch0 == 128);

  __syncthreads();   // all waves done with K-loop LDS before reuse
  float* lw = (float*)smem + wave * (16 * 68);
  const int hi = lane15 >> 2, l3 = lane15 & 3;

#pragma unroll
  for (int mi = 0; mi < 4; ++mi) {
    f32x4 v[4];
#pragma unroll
    for (int ni = 0; ni < 4; ++ni)
#pragma unroll
      for (int rg = 0; rg < 4; ++rg) v[ni][rg] = acc[mi][ni][rg] + bv[ni];

    if (ropeTile) {
      int rowB = mTile + wm + mi * 16 + quad * 4;
#pragma unroll
      for (int rg = 0; rg < 4; ++rg) {
        int ss = (rowB + rg) & 4095;
#pragma unroll
        for (int ni = 0; ni < 2; ++ni) {
          int i = ni * 16 + lane15;
          float cv = cosT[ss * 32 + i], sv = sinT[ss * 32 + i];
          float x1 = v[ni][rg], x2 = v[ni + 2][rg];
          v[ni][rg] = x1 * cv - x2 * sv;
          v[ni + 2][rg] = x2 * cv + x1 * sv;
        }
      }
    }

    if (mi) asm volatile("s_waitcnt lgkmcnt(0)" ::: "memory");
#pragma unroll
    for (int ni = 0; ni < 4; ++ni) {
      int su = (4 * ni + hi) ^ quad;   // XOR low bits by writer quad (=rr>>2)
#pragma unroll
      for (int rg = 0; rg < 4; ++rg)
        lw[68 * (quad * 4 + rg) + 4 * su + l3] = v[ni][rg];
    }
    asm volatile("s_waitcnt lgkmcnt(0)" ::: "memory");
#pragma unroll
    for (int j = 0; j < 4; ++j) {
      int rr = 4 * j + quad;
      int su = lane15 ^ j;             // un-swizzle: writer quad for row rr is j
      float4 o = *(const float4*)&lw[68 * rr + 4 * su];
      int row = mTile + wm + mi * 16 + rr;
      if (mode == 0) {
        if (colW + 4 * lane15 < 1344)
          *(float4*)(C0 + (size_t)row * 1344 + colW + 4 * lane15) = o;
      } else {
        int bb = row >> 12, ss = row & 4095;
        size_t ob =
            ((size_t)((bb * 16 + h) * 4096 + ss)) * 512 + ch0 + 4 * lane15;
        *(float4*)(out + ob) = o;
      }
    }
  }
}

// ---------- LayerNorms + k_rot broadcast ----------

__device__ __forceinline__ void reduce2(float& s1, float& s2, float* rs,
                                        float* rq) {
#pragma unroll
  for (int off = 32; off > 0; off >>= 1) {
    s1 += __shfl_down(s1, off, 64);
    s2 += __shfl_down(s2, off, 64);
  }
  int lane = threadIdx.x & 63, wave = threadIdx.x >> 6;
  if (lane == 0) { rs[wave] = s1; rq[wave] = s2; }
  __syncthreads();
  s1 = rs[0] + rs[1] + rs[2] + rs[3];
  s2 = rq[0] + rq[1] + rq[2] + rq[3];
  __syncthreads();
}

__global__ __launch_bounds__(256) void ln_rot(
    const float* __restrict__ qkvc, const float* __restrict__ g_q,
    const float* __restrict__ b_q, const float* __restrict__ g_kv,
    const float* __restrict__ b_kv, u16* __restrict__ q_ln,
    u16* __restrict__ kv_ln, const float* __restrict__ cosT,
    const float* __restrict__ sinT, float* __restrict__ out) {
  __shared__ float rs[4], rq[4];
  __shared__ __align__(16) float rot[64];
  const int t = blockIdx.x;
  const int tid = threadIdx.x;
  const int bb = t >> 12, ss = t & 4095;
  const float* p = qkvc + (size_t)t * 1344;

  // q LayerNorm (768)
  {
    float v[3], sum = 0.f, sq = 0.f;
#pragma unroll
    for (int j = 0; j < 3; ++j) {
      v[j] = p[tid + j * 256];
      sum += v[j];
      sq += v[j] * v[j];
    }
    reduce2(sum, sq, rs, rq);
    float mu = sum * (1.f / 768.f);
    float var = sq * (1.f / 768.f) - mu * mu;
    float inv = rsqrtf(var + 1e-5f);
#pragma unroll
    for (int j = 0; j < 3; ++j) {
      int c = tid + j * 256;
      q_ln[(size_t)t * 768 + c] = f2bf((v[j] - mu) * inv * g_q[c] + b_q[c]);
    }
  }
  // kv LayerNorm (512)
  {
    float v[2], sum = 0.f, sq = 0.f;
#pragma unroll
    for (int j = 0; j < 2; ++j) {
      v[j] = p[768 + tid + j * 256];
      sum += v[j];
      sq += v[j] * v[j];
    }
    reduce2(sum, sq, rs, rq);
    float mu = sum * (1.f / 512.f);
    float var = sq * (1.f / 512.f) - mu * mu;
    float inv = rsqrtf(var + 1e-5f);
#pragma unroll
    for (int j = 0; j < 2; ++j) {
      int c = tid + j * 256;
      kv_ln[(size_t)t * 512 + c] = f2bf((v[j] - mu) * inv * g_kv[c] + b_kv[c]);
    }
  }
  // k_rot (64), broadcast to 16 heads (out ch 320..383)
  if (tid < 32) {
    float k1 = p[1280 + tid], k2 = p[1312 + tid];
    float cv = cosT[ss * 32 + tid], sv = sinT[ss * 32 + tid];
    rot[tid] = k1 * cv - k2 * sv;
    rot[tid + 32] = k2 * cv + k1 * sv;
  }
  __syncthreads();
  {
    int hh = tid >> 4, c4 = tid & 15;
    float4 o = ((const float4*)rot)[c4];
    *(float4*)(out + ((size_t)((bb * 16 + hh) * 4096 + ss)) * 512 + 320 +
               4 * c4) = o;
  }
}

// ---------- launch ----------

extern "C" void kernel_launch(void* const* d_in, const int* in_sizes, int n_in,
                              void* d_out, int out_size, void* d_ws,
                              size_t ws_size, hipStream_t stream) {
  const float* hidden = (const float*)d_in[0];
  const float* w_qa = (const float*)d_in[1];
  const float* b_qa = (const float*)d_in[2];
  const float* g_qa_ln = (const float*)d_in[3];
  const float* b_qa_ln = (const float*)d_in[4];
  const float* w_qb = (const float*)d_in[5];
  const float* b_qb = (const float*)d_in[6];
  const float* w_kva = (const float*)d_in[7];
  const float* b_kva = (const float*)d_in[8];
  const float* g_kva_ln = (const float*)d_in[9];
  const float* b_kva_ln = (const float*)d_in[10];
  const float* w_kvb = (const float*)d_in[11];
  const float* b_kvb = (const float*)d_in[12];
  float* out = (float*)d_out;

  char* ws = (char*)d_ws;
  u16* hid_bf = (u16*)ws;   ws += (size_t)16777216 * 2;
  u16* wab_bf = (u16*)ws;   ws += (size_t)1344 * 2048 * 2;
  u16* wqb_bf = (u16*)ws;   ws += (size_t)2359296 * 2;
  u16* wkvb_bf = (u16*)ws;  ws += (size_t)2097152 * 2;
  float* qkvc = (float*)ws; ws += (size_t)8192 * 1344 * 4;
  u16* q_ln = (u16*)ws;     ws += (size_t)6291456 * 2;
  u16* kv_ln = (u16*)ws;    ws += (size_t)4194304 * 2;
  float* cosT = (float*)ws; ws += (size_t)131072 * 4;
  float* sinT = (float*)ws; ws += (size_t)131072 * 4;
  float* bias_ab = (float*)ws; ws += (size_t)2048 * 4;

  prep<<<dim3(1024), dim3(256), 0, stream>>>(
      hidden, w_qa, w_kva, w_qb, w_kvb, b_qa, b_kva, hid_bf, wab_bf, wqb_bf,
      wkvb_bf, bias_ab, cosT, sinT);
  // merged A-GEMM: qkvc = hidden @ [w_qa;w_kva]^T + bias  (8192 x 1344, K=2048)
  gemm_k<0><<<dim3(64, 11), dim3(256), 0, stream>>>(
      hid_bf, wab_bf, bias_ab, qkvc, nullptr, nullptr, nullptr, nullptr,
      nullptr, nullptr, nullptr, cosT, sinT);
  ln_rot<<<dim3(8192), dim3(256), 0, stream>>>(qkvc, g_qa_ln, b_qa_ln,
                                               g_kva_ln, b_kva_ln, q_ln, kv_ln,
                                               cosT, sinT, out);
  // merged B-GEMMs: y<24 -> q (N=3072,K=768, RoPE fused); y>=24 -> kv (N=4096,K=512)
  gemm_k<1><<<dim3(64, 56), dim3(256), 0, stream>>>(
      nullptr, nullptr, nullptr, nullptr, q_ln, wqb_bf, b_qb, kv_ln, wkvb_bf,
      b_kvb, out, cosT, sinT);
}